// Round 7
// baseline (36.093 us; speedup 1.0000x reference)
//
#include <hip/hip_runtime.h>

// ResizeFlow: factor-2 trilinear upsample, periodic (dft) wrap, edge anchor,
// then displacement rescale ×2 (folded into z-blend weights: 0.5/1.5).
// Input (2,3,96,96,96) f32 -> Output (2,3,192,192,192) f32.
//
// out[2k]   = 0.25*in[(k-1) mod 96] + 0.75*in[k]
// out[2k+1] = 0.75*in[k]            + 0.25*in[(k+1) mod 96]   (each axis)
//
// R7 change vs R5: fuse two adjacent z-bricks per thread -> each thread
// sweeps 8 output z-planes via a 6-input-plane sliding window
// (P(K-1)..P(K+4), K=4*tz2). The 2 planes shared between the fused bricks
// stay in REGISTERS instead of being re-loaded: 72 load instrs / 128
// outputs (was 96/128, -25%), and block count halves (10368 -> 5184).
// 3 rotating PL buffers + 3 rotating Y buffers, all statically named
// (full unroll, no runtime indexing -> no scratch).
// Unchanged: 4-row y-bricks, 4-x-quad per lane, block=64, chunked XCD
// swizzle, plain float4 stores (nt hurt: R4->R5).

#define ISZ  96
#define OSZ  192
#define NX4  48            // output-x quads per output row
#define NTY  48            // y-bricks (4 output rows each)
#define NTZ2 24            // fused z-bricks (8 output planes each)
#define ZSTR (ISZ * ISZ)

typedef float vf4 __attribute__((ext_vector_type(4)));

struct Q4 { float a, b, c, d; };          // samples at xa, xm, xm+1, xd
struct PL { Q4 r0, r1, r2, r3; };         // one input plane's 4 rows

__device__ __forceinline__ Q4 q_wsum(float wl, const Q4& L, float wh, const Q4& H) {
    Q4 q;
    q.a = fmaf(wl, L.a, wh * H.a);
    q.b = fmaf(wl, L.b, wh * H.b);
    q.c = fmaf(wl, L.c, wh * H.c);
    q.d = fmaf(wl, L.d, wh * H.d);
    return q;
}

__global__ __launch_bounds__(64)
void resize_flow_kernel(const float* __restrict__ in, float* __restrict__ out) {
    // chunked XCD swizzle (gridDim.x = 5184, divisible by 8)
    unsigned bid = blockIdx.x;
    unsigned wid = (bid & 7u) * (gridDim.x >> 3) + (bid >> 3);
    unsigned t   = wid * 64u + threadIdx.x;

    int x4 = (int)(t % NX4);
    unsigned r = t / NX4;
    int ty  = (int)(r % NTY); r /= NTY;
    int tz2 = (int)(r % NTZ2);
    int bc  = (int)(r / NTZ2);              // 0..5

    // input x indices for output quad [4*x4 .. 4*x4+3]
    int xm = 2 * x4;
    int xa = (x4 == 0)       ? ISZ - 1 : xm - 1;
    int xd = (x4 == NX4 - 1) ? 0       : xm + 2;

    // input rows for output rows [4ty .. 4ty+3]: 2ty-1 .. 2ty+2 (wrapped)
    int jy  = 2 * ty;
    int ry0 = (jy == 0) ? ISZ - 1 : jy - 1;
    int ry1 = jy, ry2 = jy + 1;
    int ry3 = (jy + 2 == ISZ) ? 0 : jy + 2;

    // input planes for output planes [8tz2 .. 8tz2+7]: K-1 .. K+4 (wrapped)
    int K  = 4 * tz2;
    int pm = (K == 0)        ? ISZ - 1 : K - 1;
    int pp = (K + 4 == ISZ)  ? 0       : K + 4;   // only tz2=23 wraps

    const float* base = in + (size_t)bc * (ISZ * ZSTR);

    auto ld = [&](const float* row) -> Q4 {
        float2 m = *reinterpret_cast<const float2*>(row + xm);  // 8B aligned
        Q4 q; q.a = row[xa]; q.b = m.x; q.c = m.y; q.d = row[xd];
        return q;
    };
    auto load_plane = [&](int p) -> PL {
        const float* pp_ = base + (size_t)p * ZSTR;
        PL L;
        L.r0 = ld(pp_ + ry0 * ISZ);
        L.r1 = ld(pp_ + ry1 * ISZ);
        L.r2 = ld(pp_ + ry2 * ISZ);
        L.r3 = ld(pp_ + ry3 * ISZ);
        return L;
    };
    // y-blend one plane's 4 rows into 4 output-y quads (oy = 4ty + i)
    auto yblend = [&](const PL& L, Q4* Y) {
        Y[0] = q_wsum(0.25f, L.r0, 0.75f, L.r1);
        Y[1] = q_wsum(0.75f, L.r1, 0.25f, L.r2);
        Y[2] = q_wsum(0.25f, L.r1, 0.75f, L.r2);
        Y[3] = q_wsum(0.75f, L.r2, 0.25f, L.r3);
    };

    int oyb = 4 * ty;
    // z-blend (×2 rescale folded into 0.5/1.5) + x-blend + 4 float4 stores
    auto store4 = [&](float wl, const Q4* YL, float wh, const Q4* YH, int oz) {
        float* pz = out + (((size_t)bc * OSZ + oz) * OSZ + oyb) * OSZ + 4 * x4;
#pragma unroll
        for (int i = 0; i < 4; ++i) {
            Q4 q = q_wsum(wl, YL[i], wh, YH[i]);
            vf4 o;
            o.x = fmaf(0.25f, q.a, 0.75f * q.b);
            o.y = fmaf(0.75f, q.b, 0.25f * q.c);
            o.z = fmaf(0.25f, q.b, 0.75f * q.c);
            o.w = fmaf(0.75f, q.c, 0.25f * q.d);
            *reinterpret_cast<vf4*>(pz + (size_t)i * OSZ) = o;
        }
    };

    // 6-plane sliding window over output planes 2K .. 2K+7:
    //   out(2k)   = 0.5*P(k-1) + 1.5*P(k)
    //   out(2k+1) = 1.5*P(k)   + 0.5*P(k+1)
    Q4 Ya[4], Yb[4], Yc[4];
    int ozb = 8 * tz2;

    PL La = load_plane(pm);
    PL Lb = load_plane(K);
    PL Lc = load_plane(K + 1);             // 3 planes in flight

    yblend(La, Ya);                         // P(K-1)
    yblend(Lb, Yb);                         // P(K)
    La = load_plane(K + 2);                 // prefetch into freed buffer
    store4(0.5f, Ya, 1.5f, Yb, ozb + 0);

    yblend(Lc, Yc);                         // P(K+1)
    store4(1.5f, Yb, 0.5f, Yc, ozb + 1);
    store4(0.5f, Yb, 1.5f, Yc, ozb + 2);
    Lb = load_plane(K + 3);                 // prefetch

    yblend(La, Ya);                         // P(K+2)
    store4(1.5f, Yc, 0.5f, Ya, ozb + 3);
    store4(0.5f, Yc, 1.5f, Ya, ozb + 4);
    Lc = load_plane(pp);                    // prefetch

    yblend(Lb, Yb);                         // P(K+3)
    store4(1.5f, Ya, 0.5f, Yb, ozb + 5);
    store4(0.5f, Ya, 1.5f, Yb, ozb + 6);

    yblend(Lc, Yc);                         // P(K+4)
    store4(1.5f, Yb, 0.5f, Yc, ozb + 7);
}

extern "C" void kernel_launch(void* const* d_in, const int* in_sizes, int n_in,
                              void* d_out, int out_size, void* d_ws, size_t ws_size,
                              hipStream_t stream) {
    const float* in = (const float*)d_in[0];
    float* out = (float*)d_out;

    // 6 * 24 * 48 * 48 = 331,776 threads; 5,184 one-wave blocks (div by 8)
    int total = 6 * NTZ2 * NTY * NX4;
    int block = 64;
    int grid  = total / block;

    resize_flow_kernel<<<grid, block, 0, stream>>>(in, out);
}